// Round 4
// baseline (171.362 us; speedup 1.0000x reference)
//
#include <hip/hip_runtime.h>

typedef float f32x4 __attribute__((ext_vector_type(4)));
typedef __bf16 bf16x8 __attribute__((ext_vector_type(8)));
typedef unsigned short us8 __attribute__((ext_vector_type(8)));
typedef unsigned short us4 __attribute__((ext_vector_type(4)));

#define QSCALE 11.541560327111707f   // 8 * log2(e) -> softmax in exp2 domain
#define NEG_INF (-__builtin_inff())

__device__ __forceinline__ float fexp2(float x) {
    return __builtin_amdgcn_exp2f(x);
}
__device__ __forceinline__ unsigned short f2bf(float x) {   // round-nearest
    unsigned u = __builtin_bit_cast(unsigned, x);
    u += 0x7fffu + ((u >> 16) & 1u);
    return (unsigned short)(u >> 16);
}
__device__ __forceinline__ float bf2f(unsigned short h) {
    unsigned u = ((unsigned)h) << 16;
    return __builtin_bit_cast(float, u);
}
__device__ __forceinline__ unsigned short bftrunc(float x) { // truncate
    return (unsigned short)(__builtin_bit_cast(unsigned, x) >> 16);
}
__device__ __forceinline__ f32x4 mfma16(us8 a, us8 b, f32x4 c) {
    return __builtin_amdgcn_mfma_f32_16x16x32_bf16(
        __builtin_bit_cast(bf16x8, a), __builtin_bit_cast(bf16x8, b), c, 0, 0, 0);
}
__device__ __forceinline__ void glds16(const unsigned short* g, unsigned short* l) {
    __builtin_amdgcn_global_load_lds(
        (const __attribute__((address_space(1))) unsigned int*)g,
        (__attribute__((address_space(3))) unsigned int*)l, 16, 0, 0);
}
// split 8 fp32 (2x float4) into hi/lo bf16 (trunc split)
__device__ __forceinline__ void splitx(float4 a, float4 b, us8& h, us8& lo) {
    float xf[8] = {a.x, a.y, a.z, a.w, b.x, b.y, b.z, b.w};
#pragma unroll
    for (int e = 0; e < 8; ++e) {
        unsigned u = __builtin_bit_cast(unsigned, xf[e]);
        h[e] = (unsigned short)(u >> 16);
        lo[e] = bftrunc(xf[e] - __builtin_bit_cast(float, u & 0xffff0000u));
    }
}

// ---------------- Kernel 0: W transpose + split (RN split) ----------------
__global__ __launch_bounds__(256) void wprep_kernel(
    const float* __restrict__ Wq, const float* __restrict__ Wk,
    const float* __restrict__ Wv,
    unsigned short* __restrict__ Wthi, unsigned short* __restrict__ Wtlo)
{
    __shared__ __align__(16) float Ls[64][68];
    const int g = blockIdx.x >> 4;
    const int k0 = (blockIdx.x & 15) << 6;
    const float* W = (g == 0) ? Wq : (g == 1) ? Wk : Wv;
    const int t = threadIdx.x;
#pragma unroll
    for (int u = 0; u < 4; ++u) {
        int idx = t + (u << 8);
        int row = idx >> 4, c4 = (idx & 15) << 2;
        *(float4*)&Ls[row][c4] = *(const float4*)&W[(size_t)(k0 + row) * 64 + c4];
    }
    __syncthreads();
    const int h = t >> 2, kk0 = (t & 3) << 4;
    size_t base = (size_t)((g << 6) + h) * 1024 + k0 + kk0;
#pragma unroll
    for (int c = 0; c < 4; ++c) {
        us4 hv, lv;
#pragma unroll
        for (int i = 0; i < 4; ++i) {
            float x = Ls[kk0 + (c << 2) + i][h];
            unsigned short hh = f2bf(x);
            hv[i] = hh;
            lv[i] = f2bf(x - bf2f(hh));
        }
        *(us4*)&Wthi[base + (c << 2)] = hv;
        *(us4*)&Wtlo[base + (c << 2)] = lv;
    }
}

// ---------------- Kernel 1: fused QKV projection ----------------
// v5: 64x48 tile, grid (256,4) = 4 blocks/CU, 4 waves/SIMD in 4 INDEPENDENT
// barrier domains (starvation fix; v4 had 2). Lean v4 structure kept:
// X direct global->reg->split (no X LDS), W hi+lo glds-staged double-buffered,
// ONE __syncthreads per K-step, everything issued early.
// Per wave: 16 unique rows x 48 cols, 3 glds + 4 X loads + 12 ds_read + 18 MFMA.
__global__ __launch_bounds__(256, 4) void qkv_kernel(
    const float* __restrict__ X,
    const unsigned short* __restrict__ Wthi,
    const unsigned short* __restrict__ Wtlo,
    unsigned short* __restrict__ Qhi, unsigned short* __restrict__ Qlo,
    unsigned short* __restrict__ Khi, unsigned short* __restrict__ Klo,
    unsigned short* __restrict__ Vthi)
{
    __shared__ __align__(16) unsigned short sm[13568];  // 26.5 KB
    unsigned short* Wh = sm;              // 2 buf x 6144 us: [hi 3072 | lo 3072]
    unsigned short* Vx = sm + 12288;      // 4x16x20 transpose scratch

    const int t = threadIdx.x;
    const int w = t >> 6, l = t & 63, lm = l & 15, lg = (l >> 4) & 3;
    const int m0 = blockIdx.x << 6;
    const int y  = blockIdx.y;            // 0..3, 48-col group

    // --- W glds staging: 12 chunks (6 hi + 6 lo, 8 rows x 64k each = 1KB) ---
    const unsigned short* wsrc[3];
    size_t woff[3];
    int gdst[3];
#pragma unroll
    for (int i = 0; i < 3; ++i) {
        int c = w * 3 + i;                      // 0..11
        int half = (c >= 6) ? 1 : 0;            // 0: hi, 1: lo
        int cc = c - 6 * half;                  // 0..5
        int n = (cc << 3) + (l >> 3);           // W row 0..47 within block
        int cg = (l & 7) ^ ((l >> 3) & 7);      // swizzled source chunk
        wsrc[i] = half ? Wtlo : Wthi;
        woff[i] = (size_t)(y * 48 + n) * 1024 + (cg << 3);
        gdst[i] = half * 3072 + (cc << 9);      // us offset in buffer
    }
    // --- X direct per-lane fragment pointer (wave owns rows w*16..w*16+16) ---
    const float* xptr = X + (size_t)(m0 + (w << 4) + lm) * 1024 + (lg << 3);

    // --- W fragment LDS offsets (swizzle: slot = (kc*4+lg) ^ (lm&7)) ---
    int boff[3][2];
#pragma unroll
    for (int ct = 0; ct < 3; ++ct)
#pragma unroll
        for (int kc = 0; kc < 2; ++kc) {
            int n = (ct << 4) + lm;
            boff[ct][kc] = (n << 6) + ((((kc << 2) + lg) ^ (lm & 7)) << 3);
        }

    f32x4 acc[3];
#pragma unroll
    for (int j = 0; j < 3; ++j) acc[j] = (f32x4){0.f, 0.f, 0.f, 0.f};

    // prologue: W(0) -> buf0; X(0) -> regs -> split
#pragma unroll
    for (int i = 0; i < 3; ++i) glds16(wsrc[i] + woff[i], Wh + gdst[i]);
    float4 xv0 = *(const float4*)(xptr);
    float4 xv1 = *(const float4*)(xptr + 4);
    float4 xv2 = *(const float4*)(xptr + 32);
    float4 xv3 = *(const float4*)(xptr + 36);
    us8 ahc[2], alc[2];
    splitx(xv0, xv1, ahc[0], alc[0]);
    splitx(xv2, xv3, ahc[1], alc[1]);
    __syncthreads();                            // buf0 visible

    for (int k = 0; k < 16; ++k) {
        const int wb = (k & 1) * 6144;
        // ---- issue-early: W(k+1) glds + X(k+1) loads, hidden under MFMA ----
        if (k < 15) {
            const int nwb = 6144 - wb;
            const size_t ko = (size_t)(k + 1) << 6;
#pragma unroll
            for (int i = 0; i < 3; ++i)
                glds16(wsrc[i] + woff[i] + ko, Wh + nwb + gdst[i]);
            const int kg = (k + 1) << 6;
            xv0 = *(const float4*)(xptr + kg);
            xv1 = *(const float4*)(xptr + kg + 4);
            xv2 = *(const float4*)(xptr + kg + 32);
            xv3 = *(const float4*)(xptr + kg + 36);
        }
        // ---- compute: 12 ds_read_b128 + 18 MFMA, all reg/LDS operands ----
        us8 bh[3][2], bl[3][2];
#pragma unroll
        for (int ct = 0; ct < 3; ++ct)
#pragma unroll
            for (int kc = 0; kc < 2; ++kc) {
                bh[ct][kc] = *(const us8*)&Wh[wb + boff[ct][kc]];
                bl[ct][kc] = *(const us8*)&Wh[wb + 3072 + boff[ct][kc]];
            }
#pragma unroll
        for (int kc = 0; kc < 2; ++kc)
#pragma unroll
            for (int ct = 0; ct < 3; ++ct) {
                acc[ct] = mfma16(ahc[kc], bh[ct][kc], acc[ct]);
                acc[ct] = mfma16(alc[kc], bh[ct][kc], acc[ct]);
                acc[ct] = mfma16(ahc[kc], bl[ct][kc], acc[ct]);
            }
        // ---- convert X(k+1) in regs (vmcnt wait covered by MFMA phase) ----
        if (k < 15) {
            splitx(xv0, xv1, ahc[0], alc[0]);
            splitx(xv2, xv3, ahc[1], alc[1]);
        }
        __syncthreads();                        // ONE barrier per K-step
    }

    // epilogue: trunc-split stores; Q pre-scaled; V transposed via Vx
    const int tbr = m0 + (w << 4);
#pragma unroll
    for (int ct = 0; ct < 3; ++ct) {
        const int gc = y * 48 + (ct << 4);
        if (gc < 128) {
            unsigned short* Dh = (gc < 64) ? Qhi : Khi;
            unsigned short* Dl = (gc < 64) ? Qlo : Klo;
            const float sc = (gc < 64) ? QSCALE : 1.0f;
            const int colb = (gc & 63) + lm;
#pragma unroll
            for (int r = 0; r < 4; ++r) {
                int row = tbr + (lg << 2) + r;
                float x = acc[ct][r] * sc;
                unsigned u = __builtin_bit_cast(unsigned, x);
                size_t o = (size_t)row * 64 + colb;
                Dh[o] = (unsigned short)(u >> 16);
                Dl[o] = bftrunc(x - __builtin_bit_cast(float, u & 0xffff0000u));
            }
        } else {
            // V: 16x16 transpose via wave-local LDS
#pragma unroll
            for (int r = 0; r < 4; ++r)
                Vx[w * 320 + lm * 20 + (lg << 2) + r] = bftrunc(acc[ct][r]);
            __asm__ volatile("" ::: "memory");
            const int h0 = gc - 128;
            const int tb = tbr;
            const int bb = tb >> 11;
            const int tl = (tb & 2047) + ((l & 3) << 2);
            const int hh2 = h0 + (l >> 2);
            us4 vv = *(const us4*)&Vx[w * 320 + (l >> 2) * 20 + ((l & 3) << 2)];
            *(us4*)&Vthi[(size_t)((bb << 6) + hh2) * 2048 + tl] = vv;
            __asm__ volatile("" ::: "memory");
        }
    }
}

// ---------------- Kernel 2: causal flash attention ----------------
// 512 blocks = (b, 32-row q-tile, heavy-first). 4 waves = 4 key-parities,
// ZERO barriers in the K-loop (K/V frags direct from global, L2-resident).
// S^T layout: lane = q-row -> softmax reduce = 15 local ops + 2 shuffles.
// exp2 domain (Q pre-scaled by 8*log2e). 4-way merge at end.
__global__ __launch_bounds__(256, 2) void attn_kernel(
    const unsigned short* __restrict__ Qhi, const unsigned short* __restrict__ Qlo,
    const unsigned short* __restrict__ Khi, const unsigned short* __restrict__ Klo,
    const unsigned short* __restrict__ Vthi,
    float* __restrict__ O)
{
    __shared__ __align__(16) unsigned char smem[33792];
    unsigned short* PS = (unsigned short*)smem;     // [4][32][72] us (loop phase)
    float* FO = (float*)smem;                       // [4][32][64] f32 (merge phase)
    float* FM = (float*)(smem + 32768);             // [4][32]
    float* FL = FM + 128;

    const int t = threadIdx.x;
    const int w = t >> 6, l = t & 63, lm = l & 15, lg = (l >> 4) & 3;
    const int b = blockIdx.x & 7;
    const int qp = 63 - (blockIdx.x >> 3);          // heavy tiles first
    const int nk = (qp >> 1) + 1;                   // 64-key tiles needed
    const int q0 = qp << 5;
    const size_t brow = (size_t)b << 11;

    // Q fragments pinned (B-operand: lane=qrow, k=lg*8+j)
    us8 qh[2][2], ql[2][2];
#pragma unroll
    for (int nt = 0; nt < 2; ++nt)
#pragma unroll
        for (int kc = 0; kc < 2; ++kc) {
            size_t off = (brow + q0 + (nt << 4) + lm) * 64 + (kc << 5) + (lg << 3);
            qh[nt][kc] = *(const us8*)&Qhi[off];
            ql[nt][kc] = *(const us8*)&Qlo[off];
        }

    f32x4 o_acc[2][4];
#pragma unroll
    for (int nt = 0; nt < 2; ++nt)
#pragma unroll
        for (int ct = 0; ct < 4; ++ct) o_acc[nt][ct] = (f32x4){0.f, 0.f, 0.f, 0.f};
    float m_r[2] = {NEG_INF, NEG_INF}, l_r[2] = {0.f, 0.f};
    unsigned short* ps = PS + w * 2304;             // wave-local 32x72

    for (int j = w; j < nk; j += 4) {
        const int kk0 = j << 6;
        us8 kh[4][2], klo[4][2], vh[4][2];
#pragma unroll
        for (int mt = 0; mt < 4; ++mt)
#pragma unroll
            for (int kc = 0; kc < 2; ++kc) {
                size_t off = (brow + kk0 + (mt << 4) + lm) * 64 + (kc << 5) + (lg << 3);
                kh[mt][kc] = *(const us8*)&Khi[off];
                klo[mt][kc] = *(const us8*)&Klo[off];
            }
#pragma unroll
        for (int ct = 0; ct < 4; ++ct)
#pragma unroll
            for (int kc = 0; kc < 2; ++kc) {
                size_t off = ((size_t)(b << 6) + (ct << 4) + lm) * 2048
                           + kk0 + (kc << 5) + (lg << 3);
                vh[ct][kc] = *(const us8*)&Vthi[off];
            }
        // S^T = K Q^T (split-bf16)
        f32x4 s[4][2];
#pragma unroll
        for (int mt = 0; mt < 4; ++mt)
#pragma unroll
            for (int nt = 0; nt < 2; ++nt) s[mt][nt] = (f32x4){0.f, 0.f, 0.f, 0.f};
#pragma unroll
        for (int kc = 0; kc < 2; ++kc)
#pragma unroll
            for (int mt = 0; mt < 4; ++mt)
#pragma unroll
                for (int nt = 0; nt < 2; ++nt) {
                    s[mt][nt] = mfma16(kh[mt][kc], qh[nt][kc], s[mt][nt]);
                    s[mt][nt] = mfma16(klo[mt][kc], qh[nt][kc], s[mt][nt]);
                    s[mt][nt] = mfma16(kh[mt][kc], ql[nt][kc], s[mt][nt]);
                }
        // online softmax (exp2 domain), lane owns row q0+nt*16+lm, 16 keys
        float alz[2];
#pragma unroll
        for (int nt = 0; nt < 2; ++nt) {
            const int qr = q0 + (nt << 4) + lm;
            float sv[16];
            if ((kk0 + 63) <= (q0 + (nt << 4))) {
#pragma unroll
                for (int mt = 0; mt < 4; ++mt)
#pragma unroll
                    for (int r = 0; r < 4; ++r) sv[(mt << 2) + r] = s[mt][nt][r];
            } else {
#pragma unroll
                for (int mt = 0; mt < 4; ++mt)
#pragma unroll
                    for (int r = 0; r < 4; ++r) {
                        const int key = kk0 + (mt << 4) + (lg << 2) + r;
                        sv[(mt << 2) + r] = (key <= qr) ? s[mt][nt][r] : NEG_INF;
                    }
            }
            float t8[8];
#pragma unroll
            for (int i = 0; i < 8; ++i) t8[i] = fmaxf(sv[i], sv[i + 8]);
#pragma unroll
            for (int i = 0; i < 4; ++i) t8[i] = fmaxf(t8[i], t8[i + 4]);
            float mx = fmaxf(fmaxf(t8[0], t8[1]), fmaxf(t8[2], t8[3]));
            mx = fmaxf(mx, __shfl_xor(mx, 16));
            mx = fmaxf(mx, __shfl_xor(mx, 32));
            const float mn = fmaxf(m_r[nt], mx);
            alz[nt] = fexp2(m_r[nt] - mn);
            m_r[nt] = mn;
            float p[16];
#pragma unroll
            for (int i = 0; i < 16; ++i) p[i] = fexp2(sv[i] - mn);
#pragma unroll
            for (int mt = 0; mt < 4; ++mt) {
                us4 pk;
#pragma unroll
                for (int r = 0; r < 4; ++r) pk[r] = bftrunc(p[(mt << 2) + r]);
                *(us4*)&ps[((nt << 4) + lm) * 72 + (mt << 4) + (lg << 2)] = pk;
            }
            float s8[8];
#pragma unroll
            for (int i = 0; i < 8; ++i) s8[i] = p[i] + p[i + 8];
#pragma unroll
            for (int i = 0; i < 4; ++i) s8[i] = s8[i] + s8[i + 4];
            float rs = (s8[0] + s8[1]) + (s8[2] + s8[3]);
            rs += __shfl_xor(rs, 16);
            rs += __shfl_xor(rs, 32);
            l_r[nt] = l_r[nt] * alz[nt] + rs;
        }
        __asm__ volatile("" ::: "memory");   // P write -> read, same wave
        // rescale O (alz lives at lane=row; fetch via shuffle)
#pragma unroll
        for (int nt = 0; nt < 2; ++nt)
#pragma unroll
            for (int r = 0; r < 4; ++r) {
                const float av = __shfl(alz[nt], (lg << 2) + r);
#pragma unroll
                for (int ct = 0; ct < 4; ++ct) o_acc[nt][ct][r] *= av;
            }
        // O += P V
#pragma unroll
        for (int nt = 0; nt < 2; ++nt)
#pragma unroll
            for (int kc = 0; kc < 2; ++kc) {
                us8 pa = *(const us8*)&ps[((nt << 4) + lm) * 72 + (kc << 5) + (lg << 3)];
#pragma unroll
                for (int ct = 0; ct < 4; ++ct)
                    o_acc[nt][ct] = mfma16(pa, vh[ct][kc], o_acc[nt][ct]);
            }
    }

    // ---- 4-way key-parity merge ----
    __syncthreads();                         // all PS use done before FO alias
#pragma unroll
    for (int nt = 0; nt < 2; ++nt)
#pragma unroll
        for (int ct = 0; ct < 4; ++ct)
#pragma unroll
            for (int r = 0; r < 4; ++r)
                FO[(w << 11) + (((nt << 4) + (lg << 2) + r) << 6) + (ct << 4) + lm]
                    = o_acc[nt][ct][r];
    if (l < 16) {
        FM[(w << 5) + lm] = m_r[0]; FM[(w << 5) + 16 + lm] = m_r[1];
        FL[(w << 5) + lm] = l_r[0]; FL[(w << 5) + 16 + lm] = l_r[1];
    }
    __syncthreads();
    const int jr = t >> 3;                   // row 0..31
    const int cg = (t & 7) << 3;             // col base
    float m0v = FM[jr], m1v = FM[32 + jr], m2v = FM[64 + jr], m3v = FM[96 + jr];
    float mm = fmaxf(fmaxf(m0v, m1v), fmaxf(m2v, m3v));
    float a0 = fexp2(m0v - mm), a1 = fexp2(m1v - mm);
    float a2 = fexp2(m2v - mm), a3 = fexp2(m3v - mm);
    float L = a0 * FL[jr] + a1 * FL[32 + jr] + a2 * FL[64 + jr] + a3 * FL[96 + jr];
    float inv = 1.0f / L;
    float ov[8];
#pragma unroll
    for (int c = 0; c < 8; ++c)
        ov[c] = a0 * FO[(jr << 6) + cg + c] + a1 * FO[2048 + (jr << 6) + cg + c]
              + a2 * FO[4096 + (jr << 6) + cg + c] + a3 * FO[6144 + (jr << 6) + cg + c];
    float4 o1 = {ov[0] * inv, ov[1] * inv, ov[2] * inv, ov[3] * inv};
    float4 o2 = {ov[4] * inv, ov[5] * inv, ov[6] * inv, ov[7] * inv};
    float* op = O + (brow + q0 + jr) * 64 + cg;
    *(float4*)op = o1;
    *(float4*)(op + 4) = o2;
}

extern "C" void kernel_launch(void* const* d_in, const int* in_sizes, int n_in,
                              void* d_out, int out_size, void* d_ws, size_t ws_size,
                              hipStream_t stream) {
    const float* X  = (const float*)d_in[0];
    const float* Wq = (const float*)d_in[1];
    const float* Wk = (const float*)d_in[2];
    const float* Wv = (const float*)d_in[3];
    unsigned short* ws = (unsigned short*)d_ws;
    const size_t SZ = (size_t)16384 * 64;
    unsigned short* Qhi  = ws;
    unsigned short* Qlo  = ws + SZ;
    unsigned short* Khi  = ws + 2 * SZ;
    unsigned short* Klo  = ws + 3 * SZ;
    unsigned short* Vthi = ws + 4 * SZ;
    unsigned short* Wthi = ws + 5 * SZ;
    unsigned short* Wtlo = Wthi + 192 * 1024;

    wprep_kernel<<<48, 256, 0, stream>>>(Wq, Wk, Wv, Wthi, Wtlo);
    qkv_kernel<<<dim3(256, 4), 256, 0, stream>>>(X, Wthi, Wtlo,
                                                 Qhi, Qlo, Khi, Klo, Vthi);
    attn_kernel<<<512, 256, 0, stream>>>(Qhi, Qlo, Khi, Klo, Vthi, (float*)d_out);
}